// Round 6
// baseline (159.494 us; speedup 1.0000x reference)
//
#include <hip/hip_runtime.h>

#define BB 128
#define NN 128
#define EE 32

// ws layout in 4-byte elements:
//  sat  : [0, 128)        f32-bits, unsigned atomicMin (init 0x7F7F7F7F by encode blk0)
//  cnt  : [128]           completion counter (init 0 by encode blk0)
//  hx   : [HX_OFF, +16384*32)  f32  (item-major rows of 32)
//  hy   : [HY_OFF, +16384*32)  f32
//  iso  : [ISO_OFF, +16384)    f32
#define SAT_OFF 0
#define CNT_OFF 128
#define HX_OFF  256
#define HY_OFF  (HX_OFF + 16384 * 32)
#define ISO_OFF (HY_OFF + 16384 * 32)

// ---------------------------------------------------------------------------
// Encode: ONE THREAD PER ITEM. 256 blocks x 64 threads = 16384 threads.
// All weight indices are thread-uniform -> compiler emits scalar (s_load)
// weight reads through the scalar cache; the contractions are register-only
// fma chains with 32 independent accumulators. No LDS, no barriers.
// ---------------------------------------------------------------------------
__global__ __launch_bounds__(64, 1) void encode_kernel(
    const float* __restrict__ boxes, const int* __restrict__ classes,
    const float* __restrict__ scores,
    const float* __restrict__ W1, const float* __restrict__ b1,
    const float* __restrict__ W2, const float* __restrict__ b2,
    const float* __restrict__ Wo1, const float* __restrict__ bo1,
    const float* __restrict__ Wo2, const float* __restrict__ bo2,
    const float* __restrict__ Ws1, float* __restrict__ ws)
{
    const int t = threadIdx.x;
    const int item = blockIdx.x * 64 + t;

    if (blockIdx.x == 0) {            // one-time init for pairs kernel
        ((unsigned*)ws)[SAT_OFF + t]      = 0x7F7F7F7Fu;  // +big sentinel
        ((unsigned*)ws)[SAT_OFF + 64 + t] = 0x7F7F7F7Fu;
        if (t == 0) ((unsigned*)ws)[CNT_OFF] = 0u;
    }

    // features: [x0,y0,x1,y1, class, score]
    const float4 bx = ((const float4*)boxes)[item];
    const float c4 = (float)classes[item];
    const float c5 = scores[item];

    // layer 1: h[e] = relu(c @ W1 + b1)   (weights uniform -> SGPR)
    float h[32];
#pragma unroll
    for (int e = 0; e < 32; e++) {
        float v = b1[e];
        v = fmaf(bx.x, W1[0 * 32 + e], v);
        v = fmaf(bx.y, W1[1 * 32 + e], v);
        v = fmaf(bx.z, W1[2 * 32 + e], v);
        v = fmaf(bx.w, W1[3 * 32 + e], v);
        v = fmaf(c4,   W1[4 * 32 + e], v);
        v = fmaf(c5,   W1[5 * 32 + e], v);
        h[e] = fmaxf(v, 0.f);
    }

    // layer 2: enc = h @ W2 + b2
    float enc[32];
#pragma unroll
    for (int e = 0; e < 32; e++) enc[e] = b2[e];
#pragma unroll
    for (int k = 0; k < 32; k++) {
        const float hk = h[k];
#pragma unroll
        for (int e = 0; e < 32; e++)
            enc[e] = fmaf(hk, W2[k * 32 + e], enc[e]);
    }

    // heads: u = relu(enc@Wo1+bo1), hx = enc@Ws1[:32], hy = enc@Ws1[32:]
    float u[32], hx[32], hy[32];
#pragma unroll
    for (int e = 0; e < 32; e++) { u[e] = bo1[e]; hx[e] = 0.f; hy[e] = 0.f; }
#pragma unroll
    for (int k = 0; k < 32; k++) {
        const float ek = enc[k];
#pragma unroll
        for (int e = 0; e < 32; e++) {
            u[e]  = fmaf(ek, Wo1[k * 32 + e], u[e]);
            hx[e] = fmaf(ek, Ws1[k * 32 + e], hx[e]);
            hy[e] = fmaf(ek, Ws1[(32 + k) * 32 + e], hy[e]);
        }
    }

    // isobj = sigmoid(relu(u) @ Wo2 + bo2)
    float z = bo2[0];
#pragma unroll
    for (int e = 0; e < 32; e++)
        z = fmaf(fmaxf(u[e], 0.f), Wo2[e], z);

    // stores: per-thread contiguous rows (float4)
    float4* ox = (float4*)(ws + HX_OFF + item * 32);
    float4* oy = (float4*)(ws + HY_OFF + item * 32);
#pragma unroll
    for (int kk = 0; kk < 8; kk++) {
        ox[kk] = make_float4(hx[4 * kk], hx[4 * kk + 1], hx[4 * kk + 2], hx[4 * kk + 3]);
        oy[kk] = make_float4(hy[4 * kk], hy[4 * kk + 1], hy[4 * kk + 2], hy[4 * kk + 3]);
    }
    ws[ISO_OFF + item] = 1.f / (1.f + __expf(-z));
}

// ---------------------------------------------------------------------------
// Pairs: grid 512 = 128 b x 4 q; block 256 = 32 i's x 8 j-lanes.
// exists_i = (1/n) * sum_{j<nb} min(iso_j, sigmoid(sum_k relu(hx+hy+bs1)*Ws2+bs2))
// outer_i = max(1-iso_i, exists_i); sat_b = min over i<nb; last block -> mean.
// ---------------------------------------------------------------------------
__global__ __launch_bounds__(256) void pairs_kernel(
    const float* __restrict__ bs1, const float* __restrict__ Ws2,
    const float* __restrict__ bs2, const int* __restrict__ num_objects,
    float* __restrict__ ws, float* __restrict__ out, int nblocks)
{
    __shared__ float hyS[128 * 36];   // stride 36 floats: rows 16B-aligned
    __shared__ float hxS[32 * 36];    // this block's 32 i-rows
    __shared__ float isoS[128];
    __shared__ float wred[4];
    __shared__ int lastFlag;
    __shared__ float r1[4], r2[4];

    const int t = threadIdx.x;
    const int b = blockIdx.x >> 2;
    const int q = blockIdx.x & 3;

    // stage hy tile + hx tile (float4) + isobj
    const float4* hyg4 = (const float4*)(ws + HY_OFF + b * 128 * 32);
#pragma unroll
    for (int it = 0; it < 4; it++) {
        const int idx = t + it * 256;                  // float4 idx 0..1023
        ((float4*)(hyS + (idx >> 3) * 36))[idx & 7] = hyg4[idx];
    }
    {
        const float4* hxg4 = (const float4*)(ws + HX_OFF + (b * 128 + q * 32) * 32);
        ((float4*)(hxS + (t >> 3) * 36))[t & 7] = hxg4[t];   // 256 f4 = 1024 floats
    }
    if (t < 128) isoS[t] = ws[ISO_OFF + b * 128 + t];
    __syncthreads();

    const int nb = num_objects[b];
    const int il = t >> 3;            // 0..31
    const int i  = q * 32 + il;
    const int s  = t & 7;

    float hxb[32];
#pragma unroll
    for (int kk = 0; kk < 8; kk++) {
        const float4 h = ((const float4*)(hxS + il * 36))[kk];
        hxb[4 * kk + 0] = h.x + bs1[4 * kk + 0];
        hxb[4 * kk + 1] = h.y + bs1[4 * kk + 1];
        hxb[4 * kk + 2] = h.z + bs1[4 * kk + 2];
        hxb[4 * kk + 3] = h.w + bs1[4 * kk + 3];
    }
    float w2[32];
#pragma unroll
    for (int k = 0; k < 32; k++) w2[k] = Ws2[k];       // wave-uniform -> SGPR
    const float bbias = bs2[0];

    float acc = 0.f;
    for (int j = s; j < nb; j += 8) {
        const float4* hr4 = (const float4*)(hyS + j * 36);
        float d0 = bbias, d1 = 0.f, d2 = 0.f, d3 = 0.f;
#pragma unroll
        for (int kk = 0; kk < 8; kk++) {
            const float4 h = hr4[kk];
            const int k0 = 4 * kk;
            d0 = fmaf(fmaxf(hxb[k0 + 0] + h.x, 0.f), w2[k0 + 0], d0);
            d1 = fmaf(fmaxf(hxb[k0 + 1] + h.y, 0.f), w2[k0 + 1], d1);
            d2 = fmaf(fmaxf(hxb[k0 + 2] + h.z, 0.f), w2[k0 + 2], d2);
            d3 = fmaf(fmaxf(hxb[k0 + 3] + h.w, 0.f), w2[k0 + 3], d3);
        }
        const float d = (d0 + d1) + (d2 + d3);
        const float same = 1.f / (1.f + __expf(-d));
        acc += fminf(isoS[j], same);
    }
    acc += __shfl_xor(acc, 1);
    acc += __shfl_xor(acc, 2);
    acc += __shfl_xor(acc, 4);

    const float exists = acc / (float)(nb > 1 ? nb : 1);
    const float outer = fmaxf(1.f - isoS[i], exists);
    float val = (i < nb) ? outer : 1.f;

    val = fminf(val, __shfl_xor(val, 8));
    val = fminf(val, __shfl_xor(val, 16));
    val = fminf(val, __shfl_xor(val, 32));
    if ((t & 63) == 0) wred[t >> 6] = val;
    __syncthreads();

    if (t == 0) {
        const float m = fminf(fminf(wred[0], wred[1]), fminf(wred[2], wred[3]));
        atomicMin((unsigned*)ws + SAT_OFF + b, __float_as_uint(m)); // vals >= 0
        __threadfence();
        const unsigned old = __hip_atomic_fetch_add((unsigned*)ws + CNT_OFF, 1u,
                                                    __ATOMIC_ACQ_REL, __HIP_MEMORY_SCOPE_AGENT);
        lastFlag = (old == (unsigned)(nblocks - 1)) ? 1 : 0;
    }
    __syncthreads();

    if (lastFlag) {
        float contrib = 0.f, vcnt = 0.f;
        if (t < 128) {
            const int nbt = num_objects[t];
            const unsigned sbits = __hip_atomic_load((unsigned*)ws + SAT_OFF + t,
                                                     __ATOMIC_RELAXED, __HIP_MEMORY_SCOPE_AGENT);
            const float sat = __uint_as_float(sbits);
            const float valid = (nbt > 0) ? 1.f : 0.f;
            contrib = sat * valid;
            vcnt = valid;
        }
#pragma unroll
        for (int off = 1; off < 64; off <<= 1) {
            contrib += __shfl_xor(contrib, off);
            vcnt += __shfl_xor(vcnt, off);
        }
        if ((t & 63) == 0) { r1[t >> 6] = contrib; r2[t >> 6] = vcnt; }
        __syncthreads();
        if (t == 0) {
            const float sc = r1[0] + r1[1] + r1[2] + r1[3];
            const float cn = r2[0] + r2[1] + r2[2] + r2[3];
            out[0] = (cn > 0.f) ? (sc / cn) : 1.f;
        }
    }
}

extern "C" void kernel_launch(void* const* d_in, const int* in_sizes, int n_in,
                              void* d_out, int out_size, void* d_ws, size_t ws_size,
                              hipStream_t stream)
{
    const float* boxes       = (const float*)d_in[0];
    const int*   classes     = (const int*)d_in[1];
    const float* scores      = (const float*)d_in[2];
    const int*   num_objects = (const int*)d_in[3];
    const float* W1  = (const float*)d_in[4];
    const float* b1  = (const float*)d_in[5];
    const float* W2  = (const float*)d_in[6];
    const float* b2  = (const float*)d_in[7];
    const float* Wo1 = (const float*)d_in[8];
    const float* bo1 = (const float*)d_in[9];
    const float* Wo2 = (const float*)d_in[10];
    const float* bo2 = (const float*)d_in[11];
    const float* Ws1 = (const float*)d_in[12];
    const float* bs1 = (const float*)d_in[13];
    const float* Ws2 = (const float*)d_in[14];
    const float* bs2 = (const float*)d_in[15];

    float* ws  = (float*)d_ws;
    float* out = (float*)d_out;

    encode_kernel<<<256, 64, 0, stream>>>(boxes, classes, scores,
                                          W1, b1, W2, b2, Wo1, bo1, Wo2, bo2,
                                          Ws1, ws);
    const int nblocks = 128 * 4;
    pairs_kernel<<<nblocks, 256, 0, stream>>>(bs1, Ws2, bs2, num_objects,
                                              ws, out, nblocks);
}

// Round 7
// 102.417 us; speedup vs baseline: 1.5573x; 1.5573x over previous
//
#include <hip/hip_runtime.h>

#define BB 128
#define NN 128
#define EE 32

// ws layout in 4-byte elements:
//  sat  : [0, 128)        f32-bits, unsigned atomicMin (init 0x7F7F7F7F by encode blk0)
//  cnt  : [128]           completion counter (init 0 by encode blk0)
//  hx   : [HX_OFF, +16384*32)  f32  (item-major rows of 32)
//  hy   : [HY_OFF, +16384*32)  f32
//  iso  : [ISO_OFF, +16384)    f32
#define SAT_OFF 0
#define CNT_OFF 128
#define HX_OFF  256
#define HY_OFF  (HX_OFF + 16384 * 32)
#define ISO_OFF (HY_OFF + 16384 * 32)

// ---------------------------------------------------------------------------
// Encode: grid 512 x 256. Lane e of each 32-lane group owns output neuron e;
// weight COLUMNS live in VGPRs (loaded once per thread, coalesced); only the
// h1/enc broadcasts round-trip through an LDS row (16B-aligned, stride 36).
// Each 32-lane group processes 4 items sequentially. No __syncthreads needed
// after staging (no weight staging at all).
// ---------------------------------------------------------------------------
__global__ __launch_bounds__(256) void encode_kernel(
    const float* __restrict__ boxes, const int* __restrict__ classes,
    const float* __restrict__ scores,
    const float* __restrict__ W1, const float* __restrict__ b1,
    const float* __restrict__ W2, const float* __restrict__ b2,
    const float* __restrict__ Wo1, const float* __restrict__ bo1,
    const float* __restrict__ Wo2, const float* __restrict__ bo2,
    const float* __restrict__ Ws1, float* __restrict__ ws)
{
    __shared__ float rows[8 * 36];     // one 144B row per 32-lane group

    const int t = threadIdx.x;
    const int e = t & 31;
    const int g = t >> 5;              // group 0..7

    if (blockIdx.x == 0) {             // one-time init for pairs kernel
        if (t < 128) ((unsigned*)ws)[SAT_OFF + t] = 0x7F7F7F7Fu;
        if (t == 128) ((unsigned*)ws)[CNT_OFF] = 0u;
    }

    // ---- weight columns into VGPRs (coalesced dword loads) ----
    float w1c[6];
#pragma unroll
    for (int f = 0; f < 6; f++) w1c[f] = W1[f * 32 + e];
    float w2c[32], wo1c[32], wsxc[32], wsyc[32];
#pragma unroll
    for (int k = 0; k < 32; k++) {
        w2c[k]  = W2[k * 32 + e];
        wo1c[k] = Wo1[k * 32 + e];
        wsxc[k] = Ws1[k * 32 + e];
        wsyc[k] = Ws1[(32 + k) * 32 + e];
    }
    const float b1e  = b1[e];
    const float b2e  = b2[e];
    const float bo1e = bo1[e];
    const float wo2e = Wo2[e];
    const float bo2s = bo2[0];

    float* row = rows + g * 36;
    const int itemBase = blockIdx.x * 32 + g * 4;

#pragma unroll 1
    for (int it = 0; it < 4; ++it) {
        const int item = itemBase + it;

        const float4 bx = ((const float4*)boxes)[item];
        const float c4 = (float)classes[item];
        const float c5 = scores[item];

        // layer 1: h1[e] = relu(c @ W1 + b1)
        float h1 = b1e;
        h1 = fmaf(bx.x, w1c[0], h1);
        h1 = fmaf(bx.y, w1c[1], h1);
        h1 = fmaf(bx.z, w1c[2], h1);
        h1 = fmaf(bx.w, w1c[3], h1);
        h1 = fmaf(c4,   w1c[4], h1);
        h1 = fmaf(c5,   w1c[5], h1);
        h1 = fmaxf(h1, 0.f);

        row[e] = h1;                               // ds_write_b32

        // layer 2: enc = h1 @ W2 + b2   (broadcast reads, 4 chains)
        float a0 = 0.f, a1 = 0.f, a2 = 0.f, a3 = 0.f;
#pragma unroll
        for (int kk = 0; kk < 8; kk++) {
            const float4 h = *(const float4*)(row + kk * 4);   // broadcast
            a0 = fmaf(h.x, w2c[4 * kk + 0], a0);
            a1 = fmaf(h.y, w2c[4 * kk + 1], a1);
            a2 = fmaf(h.z, w2c[4 * kk + 2], a2);
            a3 = fmaf(h.w, w2c[4 * kk + 3], a3);
        }
        const float enc = ((a0 + a1) + (a2 + a3)) + b2e;
        row[e] = enc;     // wave order: all h1 reads above already issued

        // heads
        float u = bo1e, hx = 0.f, hy = 0.f;
#pragma unroll
        for (int kk = 0; kk < 8; kk++) {
            const float4 ec = *(const float4*)(row + kk * 4);  // broadcast
            const int k0 = 4 * kk;
            u  = fmaf(ec.x, wo1c[k0 + 0], u);
            u  = fmaf(ec.y, wo1c[k0 + 1], u);
            u  = fmaf(ec.z, wo1c[k0 + 2], u);
            u  = fmaf(ec.w, wo1c[k0 + 3], u);
            hx = fmaf(ec.x, wsxc[k0 + 0], hx);
            hx = fmaf(ec.y, wsxc[k0 + 1], hx);
            hx = fmaf(ec.z, wsxc[k0 + 2], hx);
            hx = fmaf(ec.w, wsxc[k0 + 3], hx);
            hy = fmaf(ec.x, wsyc[k0 + 0], hy);
            hy = fmaf(ec.y, wsyc[k0 + 1], hy);
            hy = fmaf(ec.z, wsyc[k0 + 2], hy);
            hy = fmaf(ec.w, wsyc[k0 + 3], hy);
        }
        u = fmaxf(u, 0.f);

        float v = u * wo2e;
        v += __shfl_xor(v, 16, 32);
        v += __shfl_xor(v, 8, 32);
        v += __shfl_xor(v, 4, 32);
        v += __shfl_xor(v, 2, 32);
        v += __shfl_xor(v, 1, 32);

        ws[HX_OFF + item * 32 + e] = hx;
        ws[HY_OFF + item * 32 + e] = hy;
        if (e == 0)
            ws[ISO_OFF + item] = 1.f / (1.f + __expf(-(v + bo2s)));
    }
}

// ---------------------------------------------------------------------------
// Pairs: grid 256 = 128 b x 2 halves; block 256 = 32 lane-groups x 8 j-lanes.
// Each lane owns TWO i's (hxb0/hxb1 in regs) -> hy LDS reads amortized 2x.
// exists_i = (1/n) * sum_{j<nb} min(iso_j, sigmoid(sum_k relu(hx+hy+bs1)*Ws2+bs2))
// outer_i = max(1-iso_i, exists_i); sat_b = min over i<nb; last block -> mean.
// ---------------------------------------------------------------------------
__global__ __launch_bounds__(256) void pairs_kernel(
    const float* __restrict__ bs1, const float* __restrict__ Ws2,
    const float* __restrict__ bs2, const int* __restrict__ num_objects,
    float* __restrict__ ws, float* __restrict__ out, int nblocks)
{
    __shared__ float hyS[128 * 36];   // full batch-b hy, stride 36 (rows 16B-aligned)
    __shared__ float hxS[64 * 36];    // this half's 64 i-rows
    __shared__ float isoS[128];
    __shared__ float wred[4];
    __shared__ int lastFlag;
    __shared__ float r1[4], r2[4];

    const int t = threadIdx.x;
    const int b = blockIdx.x >> 1;
    const int half = blockIdx.x & 1;

    // stage hy (1024 f4) + hx (512 f4) + isobj
    const float4* hyg4 = (const float4*)(ws + HY_OFF + b * 128 * 32);
#pragma unroll
    for (int it = 0; it < 4; it++) {
        const int idx = t + it * 256;
        ((float4*)(hyS + (idx >> 3) * 36))[idx & 7] = hyg4[idx];
    }
    const float4* hxg4 = (const float4*)(ws + HX_OFF + (b * 128 + half * 64) * 32);
#pragma unroll
    for (int it = 0; it < 2; it++) {
        const int idx = t + it * 256;
        ((float4*)(hxS + (idx >> 3) * 36))[idx & 7] = hxg4[idx];
    }
    if (t < 128) isoS[t] = ws[ISO_OFF + b * 128 + t];
    __syncthreads();

    const int nb = num_objects[b];
    const int p  = t >> 3;             // 0..31 -> i-pair
    const int i0 = half * 64 + p * 2;
    const int i1 = i0 + 1;
    const int s  = t & 7;

    float hxb0[32], hxb1[32];
#pragma unroll
    for (int kk = 0; kk < 8; kk++) {
        const float4 a = ((const float4*)(hxS + (p * 2) * 36))[kk];
        const float4 c = ((const float4*)(hxS + (p * 2 + 1) * 36))[kk];
        const int k0 = 4 * kk;
        hxb0[k0 + 0] = a.x + bs1[k0 + 0];  hxb1[k0 + 0] = c.x + bs1[k0 + 0];
        hxb0[k0 + 1] = a.y + bs1[k0 + 1];  hxb1[k0 + 1] = c.y + bs1[k0 + 1];
        hxb0[k0 + 2] = a.z + bs1[k0 + 2];  hxb1[k0 + 2] = c.z + bs1[k0 + 2];
        hxb0[k0 + 3] = a.w + bs1[k0 + 3];  hxb1[k0 + 3] = c.w + bs1[k0 + 3];
    }
    float w2[32];
#pragma unroll
    for (int k = 0; k < 32; k++) w2[k] = Ws2[k];       // uniform -> s_load
    const float bbias = bs2[0];

    float acc0 = 0.f, acc1 = 0.f;
    for (int j = s; j < nb; j += 8) {
        const float4* hr4 = (const float4*)(hyS + j * 36);
        float d0 = bbias, d1 = 0.f, d2 = 0.f, d3 = 0.f;
        float e0 = bbias, e1 = 0.f, e2 = 0.f, e3 = 0.f;
#pragma unroll
        for (int kk = 0; kk < 8; kk++) {
            const float4 h = hr4[kk];
            const int k0 = 4 * kk;
            d0 = fmaf(fmaxf(hxb0[k0 + 0] + h.x, 0.f), w2[k0 + 0], d0);
            d1 = fmaf(fmaxf(hxb0[k0 + 1] + h.y, 0.f), w2[k0 + 1], d1);
            d2 = fmaf(fmaxf(hxb0[k0 + 2] + h.z, 0.f), w2[k0 + 2], d2);
            d3 = fmaf(fmaxf(hxb0[k0 + 3] + h.w, 0.f), w2[k0 + 3], d3);
            e0 = fmaf(fmaxf(hxb1[k0 + 0] + h.x, 0.f), w2[k0 + 0], e0);
            e1 = fmaf(fmaxf(hxb1[k0 + 1] + h.y, 0.f), w2[k0 + 1], e1);
            e2 = fmaf(fmaxf(hxb1[k0 + 2] + h.z, 0.f), w2[k0 + 2], e2);
            e3 = fmaf(fmaxf(hxb1[k0 + 3] + h.w, 0.f), w2[k0 + 3], e3);
        }
        const float dd = (d0 + d1) + (d2 + d3);
        const float ee = (e0 + e1) + (e2 + e3);
        const float same0 = 1.f / (1.f + __expf(-dd));
        const float same1 = 1.f / (1.f + __expf(-ee));
        const float iso_j = isoS[j];
        acc0 += fminf(iso_j, same0);
        acc1 += fminf(iso_j, same1);
    }
    acc0 += __shfl_xor(acc0, 1);  acc1 += __shfl_xor(acc1, 1);
    acc0 += __shfl_xor(acc0, 2);  acc1 += __shfl_xor(acc1, 2);
    acc0 += __shfl_xor(acc0, 4);  acc1 += __shfl_xor(acc1, 4);

    const float denom = (float)(nb > 1 ? nb : 1);
    const float ex0 = acc0 / denom;
    const float ex1 = acc1 / denom;
    const float o0 = fmaxf(1.f - isoS[i0], ex0);
    const float o1 = fmaxf(1.f - isoS[i1], ex1);
    float val = fminf((i0 < nb) ? o0 : 1.f, (i1 < nb) ? o1 : 1.f);

    val = fminf(val, __shfl_xor(val, 8));
    val = fminf(val, __shfl_xor(val, 16));
    val = fminf(val, __shfl_xor(val, 32));
    if ((t & 63) == 0) wred[t >> 6] = val;
    __syncthreads();

    if (t == 0) {
        const float m = fminf(fminf(wred[0], wred[1]), fminf(wred[2], wred[3]));
        atomicMin((unsigned*)ws + SAT_OFF + b, __float_as_uint(m)); // vals >= 0
        __threadfence();
        const unsigned old = __hip_atomic_fetch_add((unsigned*)ws + CNT_OFF, 1u,
                                                    __ATOMIC_ACQ_REL, __HIP_MEMORY_SCOPE_AGENT);
        lastFlag = (old == (unsigned)(nblocks - 1)) ? 1 : 0;
    }
    __syncthreads();

    if (lastFlag) {
        float contrib = 0.f, vcnt = 0.f;
        if (t < 128) {
            const int nbt = num_objects[t];
            const unsigned sbits = __hip_atomic_load((unsigned*)ws + SAT_OFF + t,
                                                     __ATOMIC_RELAXED, __HIP_MEMORY_SCOPE_AGENT);
            const float sat = __uint_as_float(sbits);
            const float valid = (nbt > 0) ? 1.f : 0.f;
            contrib = sat * valid;
            vcnt = valid;
        }
#pragma unroll
        for (int off = 1; off < 64; off <<= 1) {
            contrib += __shfl_xor(contrib, off);
            vcnt += __shfl_xor(vcnt, off);
        }
        if ((t & 63) == 0) { r1[t >> 6] = contrib; r2[t >> 6] = vcnt; }
        __syncthreads();
        if (t == 0) {
            const float sc = r1[0] + r1[1] + r1[2] + r1[3];
            const float cn = r2[0] + r2[1] + r2[2] + r2[3];
            out[0] = (cn > 0.f) ? (sc / cn) : 1.f;
        }
    }
}

extern "C" void kernel_launch(void* const* d_in, const int* in_sizes, int n_in,
                              void* d_out, int out_size, void* d_ws, size_t ws_size,
                              hipStream_t stream)
{
    const float* boxes       = (const float*)d_in[0];
    const int*   classes     = (const int*)d_in[1];
    const float* scores      = (const float*)d_in[2];
    const int*   num_objects = (const int*)d_in[3];
    const float* W1  = (const float*)d_in[4];
    const float* b1  = (const float*)d_in[5];
    const float* W2  = (const float*)d_in[6];
    const float* b2  = (const float*)d_in[7];
    const float* Wo1 = (const float*)d_in[8];
    const float* bo1 = (const float*)d_in[9];
    const float* Wo2 = (const float*)d_in[10];
    const float* bo2 = (const float*)d_in[11];
    const float* Ws1 = (const float*)d_in[12];
    const float* bs1 = (const float*)d_in[13];
    const float* Ws2 = (const float*)d_in[14];
    const float* bs2 = (const float*)d_in[15];

    float* ws  = (float*)d_ws;
    float* out = (float*)d_out;

    encode_kernel<<<512, 256, 0, stream>>>(boxes, classes, scores,
                                           W1, b1, W2, b2, Wo1, bo1, Wo2, bo2,
                                           Ws1, ws);
    const int nblocks = 128 * 2;
    pairs_kernel<<<nblocks, 256, 0, stream>>>(bs1, Ws2, bs2, num_objects,
                                              ws, out, nblocks);
}